// Round 12
// baseline (471.690 us; speedup 1.0000x reference)
//
#include <hip/hip_runtime.h>
#include <hip/hip_bf16.h>

using bf16 = __hip_bfloat16;
typedef __attribute__((ext_vector_type(8))) short short8;
typedef __attribute__((ext_vector_type(4))) float floatx4;
typedef __attribute__((ext_vector_type(8))) unsigned short ushort8;
typedef __attribute__((ext_vector_type(4))) int i32x4;
typedef __attribute__((ext_vector_type(8))) int i32x8;

__device__ __forceinline__ float b2f(unsigned short u) {
    union { unsigned int i; float f; } x; x.i = ((unsigned int)u) << 16; return x.f;
}

__device__ __forceinline__ void async16(const void* g, void* l) {
    __builtin_amdgcn_global_load_lds((const __attribute__((address_space(1))) void*)g,
                                     (__attribute__((address_space(3))) void*)l,
                                     16, 0, 0);
}

// float -> OCP e4m3fn, RNE, signed, |f| clamped to 448. (SW fallback)
__device__ __forceinline__ unsigned char f2e4m3(float f) {
    unsigned s = (__float_as_uint(f) >> 24) & 0x80u;
    f = fminf(fabsf(f), 448.f);
    if (f < 0.015625f) {
        int d = (int)rintf(f * 512.f);
        return (unsigned char)(s | (unsigned)d);
    }
    int E = (int)((__float_as_uint(f) >> 23) & 255u) - 127;
    float ulp_inv = __uint_as_float((unsigned)(127 + 3 - E) << 23);
    int m = (int)rintf(f * ulp_inv);
    int n = (m == 16) ? ((E + 8) << 3) : (((E + 7) << 3) + (m - 8));
    if (n > 0x7E) n = 0x7E;
    return (unsigned char)(s | (unsigned)n);
}

// pack 4 floats -> 4x e4m3 bytes via HW v_cvt_pk_fp8_f32 (OCP e4m3, RNE).
__device__ __forceinline__ unsigned int pk4_e4m3(float a, float b, float c, float d) {
#if __has_builtin(__builtin_amdgcn_cvt_pk_fp8_f32)
    int p = __builtin_amdgcn_cvt_pk_fp8_f32(a, b, 0, false);
    p = __builtin_amdgcn_cvt_pk_fp8_f32(c, d, p, true);
    return (unsigned int)p;
#else
    return (unsigned)f2e4m3(a) | ((unsigned)f2e4m3(b) << 8) |
           ((unsigned)f2e4m3(c) << 16) | ((unsigned)f2e4m3(d) << 24);
#endif
}

// gather byte rr of v0..v3 into one u32 (v_perm path, shift fallback)
__device__ __forceinline__ unsigned int perm4(unsigned v0, unsigned v1,
                                              unsigned v2, unsigned v3, int rr) {
#if __has_builtin(__builtin_amdgcn_perm)
    const unsigned sel = (unsigned)rr | ((unsigned)(rr + 4) << 8);
    const unsigned t01 = __builtin_amdgcn_perm(v1, v0, sel);
    const unsigned t23 = __builtin_amdgcn_perm(v3, v2, sel);
    return __builtin_amdgcn_perm(t23, t01, 0x05040100u);
#else
    const int s = 8 * rr;
    return ((v0 >> s) & 255u) | (((v1 >> s) & 255u) << 8) |
           (((v2 >> s) & 255u) << 16) | (((v3 >> s) & 255u) << 24);
#endif
}

// Inline dtype sniff: fp32 data read as bf16 -> ~44% wild exponents.
__device__ __forceinline__ bool sniff_wave(const unsigned short* p) {
    const int lane = threadIdx.x & 63;
    int wild = 0;
#pragma unroll
    for (int j = 0; j < 4; ++j) {
        float a = fabsf(b2f(p[lane * 4 + j]));
        wild += !(a <= 1e4f);
    }
#pragma unroll
    for (int o = 1; o < 64; o <<= 1) wild += __shfl_xor(wild, o);
    return wild > 16;
}

// ---------------------------------------------------------------------------
// Unified prep: y<18 -> dtype-convert segment y; y in [18,27) -> 512x512
// weight transpose; y in {27,28} -> 1024x256 rect transpose (Wml/Wmp);
// y in {29,30} -> mask i32 -> TRANSPOSED u8 m8T[col][row] (so scores can
// load the 4 row-bytes of a column as ONE u32 -> 4x fewer mask VMEM instr).
// ---------------------------------------------------------------------------
struct Cvt { const void* src; bf16* dst; int n; };
struct PrepArgs {
    Cvt cv[18];
    const void* tsrc[11];
    bf16* tdst[11];
    const int* msrc[2];
    unsigned char* mdst[2];
    const unsigned short* sn;
};

__global__ __launch_bounds__(256) void prep(PrepArgs a) {
    const int y = blockIdx.y;
    __shared__ bf16 tile[32][33];
    __shared__ unsigned char mt8[32][36];

    if (y >= 29) {                      // mask i32 [4096][1024] -> u8 T [1024][4096]
        const int* src = a.msrc[y - 29];
        unsigned char* dst = a.mdst[y - 29];
        const int tx = threadIdx.x & 31;
        const int ty = threadIdx.x >> 5;
        for (int tt = 0; tt < 16; ++tt) {
            const int tid = blockIdx.x * 16 + tt;    // 4096 tiles of 32x32
            const int r0 = (tid >> 5) * 32;          // < 4096
            const int c0 = (tid & 31) * 32;          // < 1024
#pragma unroll
            for (int i = 0; i < 32; i += 8)
                mt8[ty + i][tx] = src[(size_t)(r0 + ty + i) * 1024 + c0 + tx] ? 1 : 0;
            __syncthreads();
#pragma unroll
            for (int i = 0; i < 32; i += 8)
                dst[(size_t)(c0 + ty + i) * 4096 + r0 + tx] = mt8[tx][ty + i];
            __syncthreads();
        }
        return;
    }

    const bool f32 = sniff_wave(a.sn);
    if (y < 18) {
        const Cvt c = a.cv[y];
        const int stride = gridDim.x * 256 * 8;
        for (int i = (blockIdx.x * 256 + threadIdx.x) * 8; i < c.n; i += stride) {
            if (f32) {
                const float* s = (const float*)c.src + i;
#pragma unroll
                for (int j = 0; j < 8; ++j) c.dst[i + j] = __float2bfloat16(s[j]);
            } else {
                *(ushort8*)((unsigned short*)c.dst + i) =
                    *(const ushort8*)((const unsigned short*)c.src + i);
            }
        }
        return;
    }

    const int tx = threadIdx.x & 31;
    const int ty = threadIdx.x >> 5;
    if (y < 27) {                       // square 512x512, idx y-18
        const void* in = a.tsrc[y - 18];
        bf16* out = a.tdst[y - 18];
        const int bc = (blockIdx.x & 15) * 32;
        const int br = (blockIdx.x >> 4) * 32;
#pragma unroll
        for (int i = 0; i < 32; i += 8) {
            const size_t idx = (size_t)(br + ty + i) * 512 + bc + tx;
            tile[ty + i][tx] = f32 ? __float2bfloat16(((const float*)in)[idx])
                                   : ((const bf16*)in)[idx];
        }
        __syncthreads();
#pragma unroll
        for (int i = 0; i < 32; i += 8)
            out[(size_t)(bc + ty + i) * 512 + br + tx] = tile[tx][ty + i];
    } else {                            // rect 1024x256, idx y-27+9
        const void* in = a.tsrc[y - 27 + 9];
        bf16* out = a.tdst[y - 27 + 9];
        const int bc = (blockIdx.x & 7) * 32;     // < 256
        const int br = (blockIdx.x >> 3) * 32;    // < 1024
#pragma unroll
        for (int i = 0; i < 32; i += 8) {
            const size_t idx = (size_t)(br + ty + i) * 256 + bc + tx;
            tile[ty + i][tx] = f32 ? __float2bfloat16(((const float*)in)[idx])
                                   : ((const bf16*)in)[idx];
        }
        __syncthreads();
#pragma unroll
        for (int i = 0; i < 32; i += 8)
            out[(size_t)(bc + ty + i) * 1024 + br + tx] = tile[tx][ty + i];
    }
}

// ---------------------------------------------------------------------------
// Segment-table bf16 GEMM for the 3 embedding projections (BK=64, swizzled).
// ---------------------------------------------------------------------------
struct SegTab { const bf16* W[3]; const bf16* bias[3]; bf16* C[3]; int ldc[3]; int rs[3]; };

__global__ __launch_bounds__(256) void gemm_bt_seg(
    const bf16* __restrict__ A, SegTab T, int K)
{
    constexpr int TM = 2, TN = 2;
    __align__(16) __shared__ bf16 As[64 * 64];
    __align__(16) __shared__ bf16 Bs[64 * 64];

    const int lane = threadIdx.x & 63;
    const int wv   = threadIdx.x >> 6;
    const int gm   = blockIdx.y * 64;
    const int seg  = (gm >= 5120) ? 2 : ((gm >= 4096) ? 1 : 0);
    const bf16* B  = T.W[seg];
    const bf16* bias = T.bias[seg];
    bf16* C        = T.C[seg];
    const int ldc  = T.ldc[seg];
    const int m_base = gm - T.rs[seg];
    const int n_base = blockIdx.x * 64;
    const int wm0 = (wv >> 1) * 32;
    const int wn0 = (wv & 1) * 32;

    floatx4 zero = {0.f, 0.f, 0.f, 0.f};
    floatx4 acc[TM][TN];
#pragma unroll
    for (int mt = 0; mt < TM; ++mt)
#pragma unroll
        for (int nt = 0; nt < TN; ++nt) acc[mt][nt] = zero;

    const int sr  = lane >> 3;
    const int sce = ((lane & 7) ^ sr) * 8;
    const int fr  = lane & 15;
    const int q   = lane >> 4;
    const int sw  = fr & 7;

    for (int k0 = 0; k0 < K; k0 += 64) {
#pragma unroll
        for (int cc = 0; cc < 2; ++cc) {
            const int r0t = (wv + cc * 4) * 8;
            async16(A + (size_t)(gm + r0t + sr) * 512 + k0 + sce, &As[r0t * 64]);
            async16(B + (size_t)(n_base + r0t + sr) * 512 + k0 + sce, &Bs[r0t * 64]);
        }
        __syncthreads();
#pragma unroll
        for (int s = 0; s < 2; ++s) {
            const int off = ((s * 4 + q) ^ sw) * 8;
            short8 af[TM], bfr[TN];
#pragma unroll
            for (int mt = 0; mt < TM; ++mt)
                af[mt] = *(const short8*)&As[(wm0 + mt * 16 + fr) * 64 + off];
#pragma unroll
            for (int nt = 0; nt < TN; ++nt)
                bfr[nt] = *(const short8*)&Bs[(wn0 + nt * 16 + fr) * 64 + off];
#pragma unroll
            for (int mt = 0; mt < TM; ++mt)
#pragma unroll
                for (int nt = 0; nt < TN; ++nt)
                    acc[mt][nt] = __builtin_amdgcn_mfma_f32_16x16x32_bf16(
                        af[mt], bfr[nt], acc[mt][nt], 0, 0, 0);
        }
        __syncthreads();
    }

    const int er = lane >> 4;
    const int ec = lane & 15;
#pragma unroll
    for (int nt = 0; nt < TN; ++nt) {
        const int col = n_base + wn0 + nt * 16 + ec;
        const float bv = __bfloat162float(bias[col]);
#pragma unroll
        for (int mt = 0; mt < TM; ++mt)
#pragma unroll
            for (int r = 0; r < 4; ++r) {
                const int row = m_base + wm0 + mt * 16 + er * 4 + r;
                C[(size_t)row * ldc + col] = __float2bfloat16(acc[mt][nt][r] + bv);
            }
    }
}

// ---------------------------------------------------------------------------
// bf16 C = A*B^T, BK=64 swizzled, per-z args. REMAP2: z==2 remaps flat id to
// a (32,16) grid (the KV projection). BM=BN=64.
// ---------------------------------------------------------------------------
struct BtArgs { const bf16* A; const bf16* B; void* C; const bf16* bias;
                int lda, ldb, ldc; };
struct BtSet { BtArgs s[3]; };

template <bool F32OUT, bool REMAP2>
__global__ __launch_bounds__(256) void gemm_btx(BtSet P, int K, float scale)
{
    constexpr int TM = 2, TN = 2;
    __align__(16) __shared__ bf16 As[64 * 64];
    __align__(16) __shared__ bf16 Bs[64 * 64];

    const BtArgs g = P.s[blockIdx.z];
    int bx = blockIdx.x, by = blockIdx.y;
    if (REMAP2 && blockIdx.z == 2) {
        const int flat = by * gridDim.x + bx;      // 8*64 = 512
        bx = flat & 31; by = flat >> 5;            // -> (32,16)
    }
    const int lane = threadIdx.x & 63;
    const int wv   = threadIdx.x >> 6;
    const int m_base = by * 64;
    const int n_base = bx * 64;
    const int wm0 = (wv >> 1) * 32;
    const int wn0 = (wv & 1) * 32;

    floatx4 zero = {0.f, 0.f, 0.f, 0.f};
    floatx4 acc[TM][TN];
#pragma unroll
    for (int mt = 0; mt < TM; ++mt)
#pragma unroll
        for (int nt = 0; nt < TN; ++nt) acc[mt][nt] = zero;

    const int sr  = lane >> 3;
    const int sce = ((lane & 7) ^ sr) * 8;
    const int fr  = lane & 15;
    const int q   = lane >> 4;
    const int sw  = fr & 7;

    for (int k0 = 0; k0 < K; k0 += 64) {
#pragma unroll
        for (int cc = 0; cc < 2; ++cc) {
            const int r0t = (wv + cc * 4) * 8;
            async16(g.A + (size_t)(m_base + r0t + sr) * g.lda + k0 + sce, &As[r0t * 64]);
            async16(g.B + (size_t)(n_base + r0t + sr) * g.ldb + k0 + sce, &Bs[r0t * 64]);
        }
        __syncthreads();
#pragma unroll
        for (int s = 0; s < 2; ++s) {
            const int off = ((s * 4 + q) ^ sw) * 8;
            short8 af[TM], bfr[TN];
#pragma unroll
            for (int mt = 0; mt < TM; ++mt)
                af[mt] = *(const short8*)&As[(wm0 + mt * 16 + fr) * 64 + off];
#pragma unroll
            for (int nt = 0; nt < TN; ++nt)
                bfr[nt] = *(const short8*)&Bs[(wn0 + nt * 16 + fr) * 64 + off];
#pragma unroll
            for (int mt = 0; mt < TM; ++mt)
#pragma unroll
                for (int nt = 0; nt < TN; ++nt)
                    acc[mt][nt] = __builtin_amdgcn_mfma_f32_16x16x32_bf16(
                        af[mt], bfr[nt], acc[mt][nt], 0, 0, 0);
        }
        __syncthreads();
    }

    const int er = lane >> 4;
    const int ec = lane & 15;
#pragma unroll
    for (int nt = 0; nt < TN; ++nt) {
        const int col = n_base + wn0 + nt * 16 + ec;
        const float bv = __bfloat162float(g.bias[col]);
#pragma unroll
        for (int mt = 0; mt < TM; ++mt)
#pragma unroll
            for (int r = 0; r < 4; ++r) {
                const int row = m_base + wm0 + mt * 16 + er * 4 + r;
                const float v = acc[mt][nt][r] * scale + bv;
                if constexpr (F32OUT)
                    ((float*)g.C)[(size_t)row * g.ldc + col] = v;
                else
                    ((bf16*)g.C)[(size_t)row * g.ldc + col] = __float2bfloat16(v);
            }
    }
}

// ---------------------------------------------------------------------------
// Merged scores kernel, FLAT 1D grid of 5120 blocks:
//   flat <  4096: scores+mask+softmax for one 16-row slice; writes aw8
//                 row-major (u32 stores via same-wave LDS repack) AND awt
//                 in chunk-plane layout.
//   flat >= 4096: V quant-transpose (1024 blocks).
// VMEM-instruction diet (was 178/lane, issue-bound at 1.57 TB/s):
//  - mask via TRANSPOSED m8T[col][row]: 4 row-bytes = one u32 (64 u8 -> 16 u32)
//  - aw8 via LDS repack: pk u32s (4-rows-packed) staged in tbuf; each lane
//    ds_read_b128's a 4x4 tile, v_perm-gathers rows, stores 16 u32
//    (64 scalar u8 stores -> 16 u32 stores). Same-wave data: no barrier.
// ---------------------------------------------------------------------------
struct ScArgs { const bf16* Q; const bf16* K; const unsigned char* mask;
                unsigned char* aw; unsigned char* awt; };
struct ScSet { ScArgs s[2]; const bf16* vsrc[2]; unsigned char* vdst[2]; };

__global__ __launch_bounds__(256) void scores_v8(ScSet P, int ldk, float scale)
{
    __shared__ float wred[16][4];
    __shared__ float wsum[16][4];
    __shared__ float tile[32][33];
    __shared__ unsigned int tbuf[4096];    // 16KB: per-wave 1024-u32 repack buf

    const int flat = blockIdx.x;
    if (flat >= 4096) {                    // V8T transposes, 1024 blocks
        const int f2   = flat - 4096;
        const int side = f2 >> 9;
        const int rem  = f2 & 511;
        const bf16* in = P.vsrc[side];     // [1024, 2048] at V offset
        unsigned char* out = P.vdst[side];
        const int bc = (rem & 15) * 32;    // < 512
        const int br = (rem >> 4) * 32;    // < 1024
        const int tx = threadIdx.x & 31;
        const int ty = threadIdx.x >> 5;
#pragma unroll
        for (int i = 0; i < 32; i += 8)
            tile[ty + i][tx] =
                __bfloat162float(in[(size_t)(br + ty + i) * 2048 + bc + tx]) * 4.0f;
        __syncthreads();
        const unsigned int vp = pk4_e4m3(tile[tx][ty], tile[tx][ty + 8],
                                         tile[tx][ty + 16], tile[tx][ty + 24]);
#pragma unroll
        for (int i = 0; i < 4; ++i)
            out[(size_t)(bc + ty + i * 8) * 1024 + br + tx] =
                (unsigned char)(vp >> (8 * i));
        return;
    }

    const int side = flat >> 11;
    const int idx  = flat & 2047;
    const int h    = idx & 7;              // head-adjacent ordering
    const int r0   = (idx >> 3) * 16;

    const ScArgs g = P.s[side];
    const int t    = threadIdx.x;
    const int lane = t & 63;
    const int w    = t >> 6;
    const int fr   = lane & 15;
    const int fq   = lane >> 4;
    const int cbase = w * 256;

    const short* Qs = (const short*)g.Q + (size_t)(r0 + fr) * 512 + h * 64 + fq * 8;
    short8 a0 = *(const short8*)(Qs);
    short8 a1 = *(const short8*)(Qs + 32);

    floatx4 accs[16];
    const short* Kb = (const short*)g.K + h * 64 + fq * 8;
#pragma unroll
    for (int c = 0; c < 16; ++c) {
        const int krow = cbase + c * 16 + fr;
        short8 b0 = *(const short8*)(Kb + (size_t)krow * ldk);
        short8 b1 = *(const short8*)(Kb + (size_t)krow * ldk + 32);
        floatx4 acc = {0.f, 0.f, 0.f, 0.f};
        acc = __builtin_amdgcn_mfma_f32_16x16x32_bf16(a0, b0, acc, 0, 0, 0);
        acc = __builtin_amdgcn_mfma_f32_16x16x32_bf16(a1, b1, acc, 0, 0, 0);
        accs[c] = acc;
    }

    float mxr[4] = {-3e38f, -3e38f, -3e38f, -3e38f};
#pragma unroll
    for (int c = 0; c < 16; ++c) {
        const int col = cbase + c * 16 + fr;
        const unsigned int mu =
            *(const unsigned int*)(g.mask + (size_t)col * 4096 + r0 + fq * 4);
#pragma unroll
        for (int r = 0; r < 4; ++r) {
            float v = (((mu >> (8 * r)) & 255u) == 0) ? -1e9f : accs[c][r] * scale;
            accs[c][r] = v;
            mxr[r] = fmaxf(mxr[r], v);
        }
    }
#pragma unroll
    for (int o = 1; o < 16; o <<= 1)
#pragma unroll
        for (int r = 0; r < 4; ++r) mxr[r] = fmaxf(mxr[r], __shfl_xor(mxr[r], o));
    if (fr == 0)
#pragma unroll
        for (int r = 0; r < 4; ++r) wred[fq * 4 + r][w] = mxr[r];
    __syncthreads();

    float mx[4], sm[4] = {0.f, 0.f, 0.f, 0.f};
#pragma unroll
    for (int r = 0; r < 4; ++r) {
        const int row = fq * 4 + r;
        mx[r] = fmaxf(fmaxf(wred[row][0], wred[row][1]),
                      fmaxf(wred[row][2], wred[row][3]));
    }
#pragma unroll
    for (int c = 0; c < 16; ++c)
#pragma unroll
        for (int r = 0; r < 4; ++r) {
            float e = __expf(accs[c][r] - mx[r]);
            accs[c][r] = e;
            sm[r] += e;
        }
#pragma unroll
    for (int o = 1; o < 16; o <<= 1)
#pragma unroll
        for (int r = 0; r < 4; ++r) sm[r] += __shfl_xor(sm[r], o);
    if (fr == 0)
#pragma unroll
        for (int r = 0; r < 4; ++r) wsum[fq * 4 + r][w] = sm[r];
    __syncthreads();

    float inv[4];
#pragma unroll
    for (int r = 0; r < 4; ++r) {
        const int row = fq * 4 + r;
        inv[r] = 32.0f / (wsum[row][0] + wsum[row][1] + wsum[row][2] + wsum[row][3]);
    }
    unsigned char* awtb = g.awt + (size_t)(r0 >> 4) * 131072 + fq * 4;
    unsigned int* tb = &tbuf[w * 1024];
#pragma unroll
    for (int c = 0; c < 16; ++c) {
        const int col = cbase + c * 16 + fr;
        const unsigned int pk = pk4_e4m3(accs[c][0] * inv[0], accs[c][1] * inv[1],
                                         accs[c][2] * inv[2], accs[c][3] * inv[3]);
        tb[fq * 256 + c * 16 + fr] = pk;
        // chunk-plane transposed store: contiguous 256B per wave store
        *(unsigned int*)(awtb + (size_t)(h * 1024 + col) * 16) = pk;
    }
    // same-wave LDS repack: 4x4 byte-tiles -> row-major u32 stores of aw8
    unsigned char* awb = g.aw + (size_t)(r0 + fq * 4) * 8192 + h * 1024 + cbase;
#pragma unroll
    for (int tt = 0; tt < 4; ++tt) {
        const int j = tt * 16 + fr;                 // col-group (4 cols)
        const i32x4 v = *(const i32x4*)&tb[fq * 256 + 4 * j];
#pragma unroll
        for (int rr = 0; rr < 4; ++rr)
            *(unsigned int*)(awb + (size_t)rr * 8192 + 4 * j) =
                perm4((unsigned)v[0], (unsigned)v[1], (unsigned)v[2],
                      (unsigned)v[3], rr);
    }
}

// ---------------------------------------------------------------------------
// fp8 ctx GEMM (BK=64, XOR swizzle) with fused bf16 C + quantized-transposed
// CT = e4m3(C*16) output. BM=BN=64. Double-buffered, counted vmcnt(2).
// ---------------------------------------------------------------------------
struct B8Args { const unsigned char* A; const unsigned char* B; bf16* C;
                unsigned char* CT; };
struct B8Pair { B8Args s[2]; };

__global__ __launch_bounds__(256) void gemm_bt8_ctx(
    B8Pair P, int lda, long long a_kshift, int ldb, int ldc, int ldct,
    int K, float scale)
{
    constexpr int TM = 2, TN = 2;
    __align__(16) __shared__ unsigned char As[2][64 * 64];
    __align__(16) __shared__ unsigned char Bs[2][64 * 64];

    const B8Args g = P.s[blockIdx.z];
    const int lane = threadIdx.x & 63;
    const int wv   = threadIdx.x >> 6;
    const int m_base = blockIdx.y * 64;
    const int n_base = blockIdx.x * 64;
    const unsigned char* A = g.A + (long long)blockIdx.x * a_kshift;

    const int wm0 = (wv >> 1) * 32;
    const int wn0 = (wv & 1) * 32;

    floatx4 zero = {0.f, 0.f, 0.f, 0.f};
    floatx4 acc[TM][TN];
#pragma unroll
    for (int mt = 0; mt < TM; ++mt)
#pragma unroll
        for (int nt = 0; nt < TN; ++nt) acc[mt][nt] = zero;

    const int ar = lane >> 2;
    const int ac = (((lane & 3) ^ (ar & 3)) * 16);
    const int fr = lane & 15;
    const int q  = lane >> 4;
    const int sw = fr & 3;

    const int NT = K >> 6;              // 16 K-tiles (K=1024)

    auto stage = [&](int tt, int b) {
        const int k0 = tt << 6;
        async16(A + (size_t)(m_base + wv * 16 + ar) * lda + k0 + ac,
                &As[b][wv * 16 * 64]);
        async16(g.B + (size_t)(n_base + wv * 16 + ar) * ldb + k0 + ac,
                &Bs[b][wv * 16 * 64]);
    };

    stage(0, 0);
    stage(1, 1);                        // 4 loads in flight per wave

    for (int t = 0; t < NT; ++t) {
        const int cur = t & 1;
        if (t + 1 < NT)
            asm volatile("s_waitcnt vmcnt(2)\n\ts_barrier" ::: "memory");
        else
            asm volatile("s_waitcnt vmcnt(0)\n\ts_barrier" ::: "memory");

#pragma unroll
        for (int s = 0; s < 2; ++s) {
            const int boff = (((s * 2 + (q >> 1)) ^ sw) * 16) + (q & 1) * 8;
            long af[TM], bfr[TN];
#pragma unroll
            for (int mt = 0; mt < TM; ++mt)
                af[mt] = *(const long*)&As[cur][(wm0 + mt * 16 + fr) * 64 + boff];
#pragma unroll
            for (int nt = 0; nt < TN; ++nt)
                bfr[nt] = *(const long*)&Bs[cur][(wn0 + nt * 16 + fr) * 64 + boff];
#pragma unroll
            for (int mt = 0; mt < TM; ++mt)
#pragma unroll
                for (int nt = 0; nt < TN; ++nt)
                    acc[mt][nt] = __builtin_amdgcn_mfma_f32_16x16x32_fp8_fp8(
                        af[mt], bfr[nt], acc[mt][nt], 0, 0, 0);
        }
        // all waves done READING buf[cur] before anyone restages into it
        asm volatile("s_barrier" ::: "memory");
        if (t + 2 < NT) stage(t + 2, cur);
    }

    const int er = lane >> 4;
    const int ec = lane & 15;
#pragma unroll
    for (int nt = 0; nt < TN; ++nt) {
        const int col = n_base + wn0 + nt * 16 + ec;
#pragma unroll
        for (int mt = 0; mt < TM; ++mt) {
            const int rowb = m_base + wm0 + mt * 16 + er * 4;
            float v0 = fmaxf(acc[mt][nt][0] * scale, 0.f);
            float v1 = fmaxf(acc[mt][nt][1] * scale, 0.f);
            float v2 = fmaxf(acc[mt][nt][2] * scale, 0.f);
            float v3 = fmaxf(acc[mt][nt][3] * scale, 0.f);
            g.C[(size_t)(rowb + 0) * ldc + col] = __float2bfloat16(v0);
            g.C[(size_t)(rowb + 1) * ldc + col] = __float2bfloat16(v1);
            g.C[(size_t)(rowb + 2) * ldc + col] = __float2bfloat16(v2);
            g.C[(size_t)(rowb + 3) * ldc + col] = __float2bfloat16(v3);
            const unsigned int pk = pk4_e4m3(v0 * 16.f, v1 * 16.f, v2 * 16.f, v3 * 16.f);
            *(unsigned int*)(g.CT + (size_t)col * ldct + rowb) = pk;
        }
    }
}

// ---------------------------------------------------------------------------
// MX-scaled fp8 C = A*B^T, BK=128, unit e8m0 scales. ADDC0: +bf16 C0.
// FP8OUT: e4m3 row-major out; TOUT: also e4m3 transposed out (4-row u32).
// ldbk: B K-chunk stride (chunk-plane awt: ldb=16, ldbk=131072).
// DBUF: double-buffered LDS + counted vmcnt(8) (fn instantiation only).
// ---------------------------------------------------------------------------
struct MxArgs { const unsigned char* A; const unsigned char* B; void* C;
                const bf16* Cz; unsigned char* CT; };
struct MxPair { MxArgs s[2]; };

template <int BM, int BN, bool ADDC0, bool FP8OUT, bool TOUT, bool DBUF>
__global__ __launch_bounds__(256, 2) void gemm_bt8mx(
    MxPair P, int lda, int ldb, int ldbk, int ldc, int ldc0, int ldct,
    int K, float scale)
{
    constexpr int WM = BM / 2;
    constexpr int WN = BN / 2;
    constexpr int TM = WM / 16;
    constexpr int TN = WN / 16;
    static_assert(!DBUF || (BM / 32 + BN / 32) == 8, "DBUF assumes vmcnt(8)");

    __align__(16) __shared__ unsigned char As[(DBUF ? 2 : 1) * BM * 128];
    __align__(16) __shared__ unsigned char Bs[(DBUF ? 2 : 1) * BN * 128];

    const MxArgs g = P.s[blockIdx.z];
    const int lane = threadIdx.x & 63;
    const int wv   = threadIdx.x >> 6;
    const int m_base = blockIdx.y * BM;
    const int n_base = blockIdx.x * BN;

    const int wm0 = (wv >> 1) * WM;
    const int wn0 = (wv & 1) * WN;

    floatx4 zero = {0.f, 0.f, 0.f, 0.f};
    floatx4 acc[TM][TN];
#pragma unroll
    for (int mt = 0; mt < TM; ++mt)
#pragma unroll
        for (int nt = 0; nt < TN; ++nt) acc[mt][nt] = zero;

    const int sr = lane >> 3;
    const int sc = ((lane & 7) ^ sr) * 16;
    const int fr = lane & 15;
    const int q  = lane >> 4;
    const int sw = fr & 7;

    auto stage = [&](int k0, int b) {
        unsigned char* Ab = As + b * (BM * 128);
        unsigned char* Bb = Bs + b * (BN * 128);
#pragma unroll
        for (int cc = 0; cc < BM / 32; ++cc) {
            const int r0t = (wv + cc * 4) * 8;
            async16(g.A + (size_t)(m_base + r0t + sr) * lda + k0 + sc, Ab + r0t * 128);
        }
#pragma unroll
        for (int cc = 0; cc < BN / 32; ++cc) {
            const int r0t = (wv + cc * 4) * 8;
            async16(g.B + (size_t)(n_base + r0t + sr) * ldb +
                        (size_t)((k0 + sc) >> 4) * ldbk, Bb + r0t * 128);
        }
    };

    auto compute = [&](int b) {
        const unsigned char* Ab = As + b * (BM * 128);
        const unsigned char* Bb = Bs + b * (BN * 128);
        i32x8 bfr[TN];
#pragma unroll
        for (int nt = 0; nt < TN; ++nt) {
            const unsigned char* rp = &Bb[(wn0 + nt * 16 + fr) * 128];
            i32x4 lo = *(const i32x4*)(rp + (((q * 2 + 0) ^ sw) * 16));
            i32x4 hi = *(const i32x4*)(rp + (((q * 2 + 1) ^ sw) * 16));
            bfr[nt] = __builtin_shufflevector(lo, hi, 0, 1, 2, 3, 4, 5, 6, 7);
        }
#pragma unroll
        for (int mt = 0; mt < TM; ++mt) {
            const unsigned char* rp = &Ab[(wm0 + mt * 16 + fr) * 128];
            i32x4 lo = *(const i32x4*)(rp + (((q * 2 + 0) ^ sw) * 16));
            i32x4 hi = *(const i32x4*)(rp + (((q * 2 + 1) ^ sw) * 16));
            i32x8 af = __builtin_shufflevector(lo, hi, 0, 1, 2, 3, 4, 5, 6, 7);
#pragma unroll
            for (int nt = 0; nt < TN; ++nt)
                acc[mt][nt] = __builtin_amdgcn_mfma_scale_f32_16x16x128_f8f6f4(
                    af, bfr[nt], acc[mt][nt], 0, 0, 0, 127, 0, 127);
        }
    };

    if constexpr (DBUF) {
        const int NT = K >> 7;
        stage(0, 0);
        stage(128, 1);
        for (int t = 0; t < NT; ++t) {
            const int cur = t & 1;
            if (t + 1 < NT)
                asm volatile("s_waitcnt vmcnt(8)\n\ts_barrier" ::: "memory");
            else
                asm volatile("s_waitcnt vmcnt(0)\n\ts_barrier" ::: "memory");
            compute(cur);
            asm volatile("s_barrier" ::: "memory");
            if (t + 2 < NT) stage((t + 2) << 7, cur);
        }
    } else {
        for (int k0 = 0; k0 < K; k0 += 128) {
            stage(k0, 0);
            __syncthreads();
            compute(0);
            __syncthreads();
        }
    }

    const int er = lane >> 4;
    const int ec = lane & 15;
#pragma unroll
    for (int nt = 0; nt < TN; ++nt) {
        const int col = n_base + wn0 + nt * 16 + ec;
#pragma unroll
        for (int mt = 0; mt < TM; ++mt) {
            const int rowb = m_base + wm0 + mt * 16 + er * 4;
            float v[4];
#pragma unroll
            for (int r = 0; r < 4; ++r) {
                v[r] = acc[mt][nt][r] * scale;
                if constexpr (ADDC0)
                    v[r] += __bfloat162float(g.Cz[(size_t)(rowb + r) * ldc0 + col]);
            }
            if constexpr (FP8OUT) {
                const unsigned int pk = pk4_e4m3(v[0], v[1], v[2], v[3]);
#pragma unroll
                for (int r = 0; r < 4; ++r)
                    ((unsigned char*)g.C)[(size_t)(rowb + r) * ldc + col] =
                        (unsigned char)(pk >> (8 * r));
                if constexpr (TOUT)
                    *(unsigned int*)(g.CT + (size_t)col * ldct + rowb) = pk;
            } else {
#pragma unroll
                for (int r = 0; r < 4; ++r)
                    ((bf16*)g.C)[(size_t)(rowb + r) * ldc + col] = __float2bfloat16(v[r]);
            }
        }
    }
}

// ---------------------------------------------------------------------------
// Merged LayerNorm over 8192 rows x 256 cols; flag sniffed inline.
// ---------------------------------------------------------------------------
__global__ __launch_bounds__(256) void ln_all(
    const float* __restrict__ X,
    const bf16* __restrict__ g1, const bf16* __restrict__ be1,
    const bf16* __restrict__ g2, const bf16* __restrict__ be2,
    void* __restrict__ out, const unsigned short* __restrict__ sn)
{
    const bool f32 = sniff_wave(sn);
    const int lane = threadIdx.x & 63;
    const int wv   = threadIdx.x >> 6;
    const int row  = blockIdx.x * 4 + wv;
    const bf16* gg = (row >= 4096) ? g2 : g1;
    const bf16* bb = (row >= 4096) ? be2 : be1;
    const float* x = X + (size_t)row * 256;
    float v[4], s = 0.f, s2 = 0.f;
#pragma unroll
    for (int i = 0; i < 4; ++i) {
        v[i] = x[lane + 64 * i];
        s += v[i]; s2 += v[i] * v[i];
    }
#pragma unroll
    for (int o = 1; o < 64; o <<= 1) { s += __shfl_xor(s, o); s2 += __shfl_xor(s2, o); }
    const float mu  = s * (1.0f / 256.0f);
    const float var = fmaxf(s2 * (1.0f / 256.0f) - mu * mu, 0.0f);
    const float inv = rsqrtf(var + 1e-5f);
#pragma unroll
    for (int i = 0; i < 4; ++i) {
        const int c = lane + 64 * i;
        const float y = (v[i] - mu) * inv * __bfloat162float(gg[c]) + __bfloat162float(bb[c]);
        if (f32) ((float*)out)[(size_t)row * 256 + c] = y;
        else     ((bf16*)out)[(size_t)row * 256 + c] = __float2bfloat16(y);
    }
}

// ---------------------------------------------------------------------------
extern "C" void kernel_launch(void* const* d_in, const int* in_sizes, int n_in,
                              void* d_out, int out_size, void* d_ws, size_t ws_size,
                              hipStream_t stream)
{
    const int L = 4096, Mm = 1024, P = 4096;

    const int* mask_l = (const int*)d_in[3];
    const int* mask_p = (const int*)d_in[4];
    const unsigned short* sn = (const unsigned short*)d_in[0];

    char* ws = (char*)d_ws;
    size_t off = 0;
    auto alloc = [&](size_t bytes) {
        void* p = ws + off; off += (bytes + 255) & ~(size_t)255; return p;
    };

    // weight slots: 0:Wl 1:Wm 2:Wp 3:Wql 4:Wqp 5:Wkl 6:Wvl 7:Wkp 8:Wvp
    bf16* wt_all = (bf16*)alloc((size_t)9 * 512 * 512 * 2);
    bf16* WmlT   = (bf16*)alloc(1024 * 256 * 2);
    bf16* WmpT   = (bf16*)alloc(1024 * 256 * 2);
    bf16* b_l    = (bf16*)alloc(512 * 2);
    bf16* b_m    = (bf16*)alloc(512 * 2);
    bf16* b_p    = (bf16*)alloc(512 * 2);
    bf16* b_ql   = (bf16*)alloc(512 * 2);
    bf16* b_qp   = (bf16*)alloc(512 * 2);
    bf16* bcat   = (bf16*)alloc(2048 * 2);     // [bkl|bvl|bkp|bvp]
    bf16* bml_c  = (bf16*)alloc(256 * 2);
    bf16* bmp_c  = (bf16*)alloc(256 * 2);
    bf16* g1c    = (bf16*)alloc(256 * 2);
    bf16* be1c   = (bf16*)alloc(256 * 2);
    bf16* g2c    = (bf16*)alloc(256 * 2);
    bf16* be2c   = (bf16*)alloc(256 * 2);
    bf16* emb_all = (bf16*)alloc((size_t)(L + Mm + P) * 512 * 2);  // [l|m|p]
    bf16* embl   = emb_all;
    bf16* embm   = emb_all + (size_t)L * 512;
    bf16* embp   = embm + (size_t)Mm * 512;
    bf16* cat_l  = (bf16*)alloc((size_t)L * 1024 * 2);   // [lt | fin_l]
    bf16* cat_p  = (bf16*)alloc((size_t)P * 1024 * 2);   // [fin_p | pt]
    bf16* mt     = (bf16*)alloc((size_t)Mm * 512 * 2);
    bf16* Ql     = (bf16*)alloc((size_t)L * 512 * 2);
    bf16* Qp     = (bf16*)alloc((size_t)P * 512 * 2);
    bf16* kvcat  = (bf16*)alloc((size_t)Mm * 2048 * 2);  // [Kl|Vl|Kp|Vp]
    unsigned char* V8lT = (unsigned char*)alloc((size_t)512 * Mm);
    unsigned char* V8pT = (unsigned char*)alloc((size_t)512 * Mm);
    bf16* ctx_l  = (bf16*)alloc((size_t)L * 512 * 2);
    bf16* ctx_p  = (bf16*)alloc((size_t)P * 512 * 2);
    unsigned char* ctx8lT = (unsigned char*)alloc((size_t)512 * L);
    unsigned char* ctx8pT = (unsigned char*)alloc((size_t)512 * P);
    unsigned char* awlT8  = (unsigned char*)alloc((size_t)8192 * 4096);  // aw_l^T planes
    unsigned char* awpT8  = (unsigned char*)alloc((size_t)8192 * 4096);  // aw_p^T planes
    unsigned char* awl8 = (unsigned char*)alloc((size_t)L * 8192);
    unsigned char* awp8 = (unsigned char*)alloc((size_t)P * 8192);
    unsigned char* m8l  = (unsigned char*)alloc((size_t)1024 * 4096);    // mask u8 T
    unsigned char* m8p  = (unsigned char*)alloc((size_t)1024 * 4096);
    // overlays: emb_all dead after step 2 -> hosts T1 (8MB <= 9.4MB);
    // awp8 dead after step 7 -> tmp written in step 8
    unsigned char* T1lT = (unsigned char*)emb_all;                       // [512,8192]
    unsigned char* T1pT = (unsigned char*)emb_all + (size_t)512 * 8192;  // [512,8192]
    float* tmp1 = (float*)awp8;                          // [8192, 256] fp32

    // 1. unified prep: 18 converts + 9 square + 2 rect transposes + 2 masks
    PrepArgs pa;
    pa.sn = sn;
    pa.cv[0]  = { d_in[0],  embl, L * 512 };
    pa.cv[1]  = { d_in[1],  embm, Mm * 512 };
    pa.cv[2]  = { d_in[2],  embp, P * 512 };
    pa.cv[3]  = { d_in[6],  b_l,  512 };
    pa.cv[4]  = { d_in[8],  b_m,  512 };
    pa.cv[5]  = { d_in[10], b_p,  512 };
    pa.cv[6]  = { d_in[12], b_ql, 512 };
    pa.cv[7]  = { d_in[18], b_qp, 512 };
    pa.cv[8]  = { d_in[14], bcat,        512 };
    pa.cv[9]  = { d_in[16], bcat + 512,  512 };
    pa.cv[10] = { d_in[20], bcat + 1024, 512 };
    pa.cv[11] = { d_in[22], bcat + 1536, 512 };
    pa.cv[12] = { d_in[24], bml_c, 256 };
    pa.cv[13] = { d_in[26], bmp_c, 256 };
    pa.cv[14] = { d_in[27], g1c,  256 };
    pa.cv[15] = { d_in[28], be1c, 256 };
    pa.cv[16] = { d_in[29], g2c,  256 };
    pa.cv[17] = { d_in[30], be2c, 256 };
    const int slot_of[9] = {0, 1, 2, 3, 5, 6, 4, 7, 8};
    for (int i = 0; i < 9; ++i) {
        pa.tsrc[i] = d_in[5 + 2 * i];
        pa.tdst[i] = wt_all + (size_t)slot_of[i] * 512 * 512;
    }
    pa.tsrc[9]  = d_in[23]; pa.tdst[9]  = WmlT;
    pa.tsrc[10] = d_in[25]; pa.tdst[10] = WmpT;
    pa.msrc[0] = mask_l; pa.mdst[0] = m8l;
    pa.msrc[1] = mask_p; pa.mdst[1] = m8p;
    prep<<<dim3(256, 31), 256, 0, stream>>>(pa);

    bf16* WlT  = wt_all;
    bf16* WmT  = wt_all + (size_t)1 * 512 * 512;
    bf16* WpT  = wt_all + (size_t)2 * 512 * 512;
    bf16* WqlT = wt_all + (size_t)3 * 512 * 512;
    bf16* WqpT = wt_all + (size_t)4 * 512 * 512;
    bf16* WkvT = wt_all + (size_t)5 * 512 * 512;  // [2048, 512]

    // 2. embedding projections (segment table)
    SegTab st;
    st.W[0] = WlT;  st.bias[0] = b_l; st.C[0] = cat_l;       st.ldc[0] = 1024; st.rs[0] = 0;
    st.W[1] = WmT;  st.bias[1] = b_m; st.C[1] = mt;          st.ldc[1] = 512;  st.rs[1] = 4096;
    st.W[2] = WpT;  st.bias[2] = b_p; st.C[2] = cat_p + 512; st.ldc[2] = 1024; st.rs[2] = 5120;
    gemm_bt_seg<<<dim3(8, 144), 256, 0, stream>>>(emb_all, st, 512);

    // 3. Q projections + KV projection, one launch (z=2 remapped to 32x16)
    BtSet qs;
    qs.s[0] = { cat_l,       WqlT, Ql,    b_ql, 1024, 512, 512 };
    qs.s[1] = { cat_p + 512, WqpT, Qp,    b_qp, 1024, 512, 512 };
    qs.s[2] = { mt,          WkvT, kvcat, bcat, 512,  512, 2048 };
    gemm_btx<false, true><<<dim3(8, 64, 3), 256, 0, stream>>>(qs, 512, 1.0f);

    // 4. scores+softmax + awT (chunk-plane) + V transpose; transposed u8
    //    mask (u32 loads), LDS-repacked aw8 (u32 stores)
    ScSet sc;
    sc.s[0] = { Ql, kvcat,        m8l, awl8, awlT8 };
    sc.s[1] = { Qp, kvcat + 1024, m8p, awp8, awpT8 };
    sc.vsrc[0] = kvcat + 512;  sc.vdst[0] = V8lT;
    sc.vsrc[1] = kvcat + 1536; sc.vdst[1] = V8pT;
    scores_v8<<<dim3(5120), 256, 0, stream>>>(sc, 2048, 0.125f);

    // 5. ctx = relu(aw @ V) per head, fused ctx8T = e4m3(ctx^T*16);
    //    double-buffered counted-vmcnt K-loop
    B8Pair cx = { { { awl8, V8lT, ctx_l, ctx8lT },
                    { awp8, V8pT, ctx_p, ctx8pT } } };
    gemm_bt8_ctx<<<dim3(8, 64, 2), 256, 0, stream>>>(
        cx, 8192, 1024, 1024, 512, 4096, 1024, 1.0f / 128.0f);

    // 6. RE-ASSOCIATED mutual path: T1lT = ctx8pT @ awpT8^T, K=p=4096.
    //    Tall tile BM=512: awt B-panel read exactly once. Single-buffer.
    MxPair t1 = { { { ctx8pT, awpT8, T1lT, nullptr, nullptr },
                    { ctx8lT, awlT8, T1pT, nullptr, nullptr } } };
    gemm_bt8mx<512, 64, false, true, false, false><<<dim3(128, 1, 2), 256, 0, stream>>>(
        t1, 4096, 16, 131072, 8192, 0, 0, 4096, 1.0f / 128.0f);

    // 7. fn = ctx + (aw @ T1)/8, K=8192; DBUF counted-vmcnt pipeline
    MxPair fn = { { { awl8, T1lT, cat_l + 512, ctx_l, nullptr },
                    { awp8, T1pT, cat_p,       ctx_p, nullptr } } };
    gemm_bt8mx<128, 128, true, false, false, true><<<dim3(4, 32, 2), 256, 0, stream>>>(
        fn, 8192, 8192, 16, 1024, 512, 0, 8192, 1.0f / 1024.0f);

    // 8. final projections (pair, fp32 out)
    BtSet fp;
    fp.s[0] = { cat_l, WmlT, tmp1,                   bml_c, 1024, 1024, 256 };
    fp.s[1] = { cat_p, WmpT, tmp1 + (size_t)L * 256, bmp_c, 1024, 1024, 256 };
    fp.s[2] = fp.s[0];
    gemm_btx<true, false><<<dim3(4, 64, 2), 256, 0, stream>>>(fp, 1024, 1.0f);

    // 9. merged LayerNorm -> d_out
    ln_all<<<dim3(2048), 256, 0, stream>>>(tmp1, g1c, be1c, g2c, be2c, d_out, sn);
}

// Round 13
// 452.725 us; speedup vs baseline: 1.0419x; 1.0419x over previous
//
#include <hip/hip_runtime.h>
#include <hip/hip_bf16.h>

using bf16 = __hip_bfloat16;
typedef __attribute__((ext_vector_type(8))) short short8;
typedef __attribute__((ext_vector_type(4))) float floatx4;
typedef __attribute__((ext_vector_type(8))) unsigned short ushort8;
typedef __attribute__((ext_vector_type(4))) int i32x4;
typedef __attribute__((ext_vector_type(8))) int i32x8;

__device__ __forceinline__ float b2f(unsigned short u) {
    union { unsigned int i; float f; } x; x.i = ((unsigned int)u) << 16; return x.f;
}

__device__ __forceinline__ void async16(const void* g, void* l) {
    __builtin_amdgcn_global_load_lds((const __attribute__((address_space(1))) void*)g,
                                     (__attribute__((address_space(3))) void*)l,
                                     16, 0, 0);
}

// float -> OCP e4m3fn, RNE, signed, |f| clamped to 448. (SW fallback)
__device__ __forceinline__ unsigned char f2e4m3(float f) {
    unsigned s = (__float_as_uint(f) >> 24) & 0x80u;
    f = fminf(fabsf(f), 448.f);
    if (f < 0.015625f) {
        int d = (int)rintf(f * 512.f);
        return (unsigned char)(s | (unsigned)d);
    }
    int E = (int)((__float_as_uint(f) >> 23) & 255u) - 127;
    float ulp_inv = __uint_as_float((unsigned)(127 + 3 - E) << 23);
    int m = (int)rintf(f * ulp_inv);
    int n = (m == 16) ? ((E + 8) << 3) : (((E + 7) << 3) + (m - 8));
    if (n > 0x7E) n = 0x7E;
    return (unsigned char)(s | (unsigned)n);
}

// pack 4 floats -> 4x e4m3 bytes via HW v_cvt_pk_fp8_f32 (OCP e4m3, RNE).
__device__ __forceinline__ unsigned int pk4_e4m3(float a, float b, float c, float d) {
#if __has_builtin(__builtin_amdgcn_cvt_pk_fp8_f32)
    int p = __builtin_amdgcn_cvt_pk_fp8_f32(a, b, 0, false);
    p = __builtin_amdgcn_cvt_pk_fp8_f32(c, d, p, true);
    return (unsigned int)p;
#else
    return (unsigned)f2e4m3(a) | ((unsigned)f2e4m3(b) << 8) |
           ((unsigned)f2e4m3(c) << 16) | ((unsigned)f2e4m3(d) << 24);
#endif
}

// Inline dtype sniff: fp32 data read as bf16 -> ~44% wild exponents.
__device__ __forceinline__ bool sniff_wave(const unsigned short* p) {
    const int lane = threadIdx.x & 63;
    int wild = 0;
#pragma unroll
    for (int j = 0; j < 4; ++j) {
        float a = fabsf(b2f(p[lane * 4 + j]));
        wild += !(a <= 1e4f);
    }
#pragma unroll
    for (int o = 1; o < 64; o <<= 1) wild += __shfl_xor(wild, o);
    return wild > 16;
}

// ---------------------------------------------------------------------------
// Unified prep: y<18 -> dtype-convert segment y; y in [18,27) -> 512x512
// weight transpose; y in {27,28} -> 1024x256 rect transpose (Wml/Wmp);
// y in {29,30} -> mask i32 -> u8 compaction (4x less mask read traffic).
// ---------------------------------------------------------------------------
struct Cvt { const void* src; bf16* dst; int n; };
struct PrepArgs {
    Cvt cv[18];
    const void* tsrc[11];
    bf16* tdst[11];
    const int* msrc[2];
    unsigned char* mdst[2];
    const unsigned short* sn;
};

__global__ __launch_bounds__(256) void prep(PrepArgs a) {
    const int y = blockIdx.y;
    __shared__ bf16 tile[32][33];

    if (y >= 29) {                      // mask i32 -> u8, 4M elements
        const int* src = a.msrc[y - 29];
        unsigned char* dst = a.mdst[y - 29];
        const int n = 4096 * 1024;
        const int stride = gridDim.x * 256 * 16;
        for (int i = (blockIdx.x * 256 + threadIdx.x) * 16; i < n; i += stride) {
            union { unsigned char b[16]; i32x4 v; } u;
#pragma unroll
            for (int j = 0; j < 4; ++j) {
                i32x4 m = *(const i32x4*)(src + i + j * 4);
#pragma unroll
                for (int k = 0; k < 4; ++k) u.b[j * 4 + k] = m[k] ? 1 : 0;
            }
            *(i32x4*)(dst + i) = u.v;
        }
        return;
    }

    const bool f32 = sniff_wave(a.sn);
    if (y < 18) {
        const Cvt c = a.cv[y];
        const int stride = gridDim.x * 256 * 8;
        for (int i = (blockIdx.x * 256 + threadIdx.x) * 8; i < c.n; i += stride) {
            if (f32) {
                const float* s = (const float*)c.src + i;
#pragma unroll
                for (int j = 0; j < 8; ++j) c.dst[i + j] = __float2bfloat16(s[j]);
            } else {
                *(ushort8*)((unsigned short*)c.dst + i) =
                    *(const ushort8*)((const unsigned short*)c.src + i);
            }
        }
        return;
    }

    const int tx = threadIdx.x & 31;
    const int ty = threadIdx.x >> 5;
    if (y < 27) {                       // square 512x512, idx y-18
        const void* in = a.tsrc[y - 18];
        bf16* out = a.tdst[y - 18];
        const int bc = (blockIdx.x & 15) * 32;
        const int br = (blockIdx.x >> 4) * 32;
#pragma unroll
        for (int i = 0; i < 32; i += 8) {
            const size_t idx = (size_t)(br + ty + i) * 512 + bc + tx;
            tile[ty + i][tx] = f32 ? __float2bfloat16(((const float*)in)[idx])
                                   : ((const bf16*)in)[idx];
        }
        __syncthreads();
#pragma unroll
        for (int i = 0; i < 32; i += 8)
            out[(size_t)(bc + ty + i) * 512 + br + tx] = tile[tx][ty + i];
    } else {                            // rect 1024x256, idx y-27+9
        const void* in = a.tsrc[y - 27 + 9];
        bf16* out = a.tdst[y - 27 + 9];
        const int bc = (blockIdx.x & 7) * 32;     // < 256
        const int br = (blockIdx.x >> 3) * 32;    // < 1024
#pragma unroll
        for (int i = 0; i < 32; i += 8) {
            const size_t idx = (size_t)(br + ty + i) * 256 + bc + tx;
            tile[ty + i][tx] = f32 ? __float2bfloat16(((const float*)in)[idx])
                                   : ((const bf16*)in)[idx];
        }
        __syncthreads();
#pragma unroll
        for (int i = 0; i < 32; i += 8)
            out[(size_t)(bc + ty + i) * 1024 + br + tx] = tile[tx][ty + i];
    }
}

// ---------------------------------------------------------------------------
// Segment-table bf16 GEMM for the 3 embedding projections (BK=64, swizzled).
// ---------------------------------------------------------------------------
struct SegTab { const bf16* W[3]; const bf16* bias[3]; bf16* C[3]; int ldc[3]; int rs[3]; };

__global__ __launch_bounds__(256) void gemm_bt_seg(
    const bf16* __restrict__ A, SegTab T, int K)
{
    constexpr int TM = 2, TN = 2;
    __align__(16) __shared__ bf16 As[64 * 64];
    __align__(16) __shared__ bf16 Bs[64 * 64];

    const int lane = threadIdx.x & 63;
    const int wv   = threadIdx.x >> 6;
    const int gm   = blockIdx.y * 64;
    const int seg  = (gm >= 5120) ? 2 : ((gm >= 4096) ? 1 : 0);
    const bf16* B  = T.W[seg];
    const bf16* bias = T.bias[seg];
    bf16* C        = T.C[seg];
    const int ldc  = T.ldc[seg];
    const int m_base = gm - T.rs[seg];
    const int n_base = blockIdx.x * 64;
    const int wm0 = (wv >> 1) * 32;
    const int wn0 = (wv & 1) * 32;

    floatx4 zero = {0.f, 0.f, 0.f, 0.f};
    floatx4 acc[TM][TN];
#pragma unroll
    for (int mt = 0; mt < TM; ++mt)
#pragma unroll
        for (int nt = 0; nt < TN; ++nt) acc[mt][nt] = zero;

    const int sr  = lane >> 3;
    const int sce = ((lane & 7) ^ sr) * 8;
    const int fr  = lane & 15;
    const int q   = lane >> 4;
    const int sw  = fr & 7;

    for (int k0 = 0; k0 < K; k0 += 64) {
#pragma unroll
        for (int cc = 0; cc < 2; ++cc) {
            const int r0t = (wv + cc * 4) * 8;
            async16(A + (size_t)(gm + r0t + sr) * 512 + k0 + sce, &As[r0t * 64]);
            async16(B + (size_t)(n_base + r0t + sr) * 512 + k0 + sce, &Bs[r0t * 64]);
        }
        __syncthreads();
#pragma unroll
        for (int s = 0; s < 2; ++s) {
            const int off = ((s * 4 + q) ^ sw) * 8;
            short8 af[TM], bfr[TN];
#pragma unroll
            for (int mt = 0; mt < TM; ++mt)
                af[mt] = *(const short8*)&As[(wm0 + mt * 16 + fr) * 64 + off];
#pragma unroll
            for (int nt = 0; nt < TN; ++nt)
                bfr[nt] = *(const short8*)&Bs[(wn0 + nt * 16 + fr) * 64 + off];
#pragma unroll
            for (int mt = 0; mt < TM; ++mt)
#pragma unroll
                for (int nt = 0; nt < TN; ++nt)
                    acc[mt][nt] = __builtin_amdgcn_mfma_f32_16x16x32_bf16(
                        af[mt], bfr[nt], acc[mt][nt], 0, 0, 0);
        }
        __syncthreads();
    }

    const int er = lane >> 4;
    const int ec = lane & 15;
#pragma unroll
    for (int nt = 0; nt < TN; ++nt) {
        const int col = n_base + wn0 + nt * 16 + ec;
        const float bv = __bfloat162float(bias[col]);
#pragma unroll
        for (int mt = 0; mt < TM; ++mt)
#pragma unroll
            for (int r = 0; r < 4; ++r) {
                const int row = m_base + wm0 + mt * 16 + er * 4 + r;
                C[(size_t)row * ldc + col] = __float2bfloat16(acc[mt][nt][r] + bv);
            }
    }
}

// ---------------------------------------------------------------------------
// bf16 C = A*B^T, BK=64 swizzled, per-z args. REMAP2: z==2 remaps flat id to
// a (32,16) grid (the KV projection). BM=BN=64.
// ---------------------------------------------------------------------------
struct BtArgs { const bf16* A; const bf16* B; void* C; const bf16* bias;
                int lda, ldb, ldc; };
struct BtSet { BtArgs s[3]; };

template <bool F32OUT, bool REMAP2>
__global__ __launch_bounds__(256) void gemm_btx(BtSet P, int K, float scale)
{
    constexpr int TM = 2, TN = 2;
    __align__(16) __shared__ bf16 As[64 * 64];
    __align__(16) __shared__ bf16 Bs[64 * 64];

    const BtArgs g = P.s[blockIdx.z];
    int bx = blockIdx.x, by = blockIdx.y;
    if (REMAP2 && blockIdx.z == 2) {
        const int flat = by * gridDim.x + bx;      // 8*64 = 512
        bx = flat & 31; by = flat >> 5;            // -> (32,16)
    }
    const int lane = threadIdx.x & 63;
    const int wv   = threadIdx.x >> 6;
    const int m_base = by * 64;
    const int n_base = bx * 64;
    const int wm0 = (wv >> 1) * 32;
    const int wn0 = (wv & 1) * 32;

    floatx4 zero = {0.f, 0.f, 0.f, 0.f};
    floatx4 acc[TM][TN];
#pragma unroll
    for (int mt = 0; mt < TM; ++mt)
#pragma unroll
        for (int nt = 0; nt < TN; ++nt) acc[mt][nt] = zero;

    const int sr  = lane >> 3;
    const int sce = ((lane & 7) ^ sr) * 8;
    const int fr  = lane & 15;
    const int q   = lane >> 4;
    const int sw  = fr & 7;

    for (int k0 = 0; k0 < K; k0 += 64) {
#pragma unroll
        for (int cc = 0; cc < 2; ++cc) {
            const int r0t = (wv + cc * 4) * 8;
            async16(g.A + (size_t)(m_base + r0t + sr) * g.lda + k0 + sce, &As[r0t * 64]);
            async16(g.B + (size_t)(n_base + r0t + sr) * g.ldb + k0 + sce, &Bs[r0t * 64]);
        }
        __syncthreads();
#pragma unroll
        for (int s = 0; s < 2; ++s) {
            const int off = ((s * 4 + q) ^ sw) * 8;
            short8 af[TM], bfr[TN];
#pragma unroll
            for (int mt = 0; mt < TM; ++mt)
                af[mt] = *(const short8*)&As[(wm0 + mt * 16 + fr) * 64 + off];
#pragma unroll
            for (int nt = 0; nt < TN; ++nt)
                bfr[nt] = *(const short8*)&Bs[(wn0 + nt * 16 + fr) * 64 + off];
#pragma unroll
            for (int mt = 0; mt < TM; ++mt)
#pragma unroll
                for (int nt = 0; nt < TN; ++nt)
                    acc[mt][nt] = __builtin_amdgcn_mfma_f32_16x16x32_bf16(
                        af[mt], bfr[nt], acc[mt][nt], 0, 0, 0);
        }
        __syncthreads();
    }

    const int er = lane >> 4;
    const int ec = lane & 15;
#pragma unroll
    for (int nt = 0; nt < TN; ++nt) {
        const int col = n_base + wn0 + nt * 16 + ec;
        const float bv = __bfloat162float(g.bias[col]);
#pragma unroll
        for (int mt = 0; mt < TM; ++mt)
#pragma unroll
            for (int r = 0; r < 4; ++r) {
                const int row = m_base + wm0 + mt * 16 + er * 4 + r;
                const float v = acc[mt][nt][r] * scale + bv;
                if constexpr (F32OUT)
                    ((float*)g.C)[(size_t)row * g.ldc + col] = v;
                else
                    ((bf16*)g.C)[(size_t)row * g.ldc + col] = __float2bfloat16(v);
            }
    }
}

// ---------------------------------------------------------------------------
// Merged scores kernel, FLAT 1D grid of 5120 blocks:
//   flat <  4096: scores+mask+softmax for one 16-row slice; writes aw8
//                 row-major AND awt in CHUNK-PLANE layout.
//   flat >= 4096: V quant-transpose (1024 blocks).
// HEAD-ADJACENT decode (h = flat&7); mask pre-compacted to u8; awt
// chunk-plane layout [p>>4][m][p&15] -> contiguous 16KB block writes;
// fp8 quantization via HW v_cvt_pk_fp8_f32.
// ---------------------------------------------------------------------------
struct ScArgs { const bf16* Q; const bf16* K; const unsigned char* mask;
                unsigned char* aw; unsigned char* awt; };
struct ScSet { ScArgs s[2]; const bf16* vsrc[2]; unsigned char* vdst[2]; };

__global__ __launch_bounds__(256) void scores_v8(ScSet P, int ldk, float scale)
{
    __shared__ float wred[16][4];
    __shared__ float wsum[16][4];
    __shared__ float tile[32][33];

    const int flat = blockIdx.x;
    if (flat >= 4096) {                    // V8T transposes, 1024 blocks
        const int f2   = flat - 4096;
        const int side = f2 >> 9;
        const int rem  = f2 & 511;
        const bf16* in = P.vsrc[side];     // [1024, 2048] at V offset
        unsigned char* out = P.vdst[side];
        const int bc = (rem & 15) * 32;    // < 512
        const int br = (rem >> 4) * 32;    // < 1024
        const int tx = threadIdx.x & 31;
        const int ty = threadIdx.x >> 5;
#pragma unroll
        for (int i = 0; i < 32; i += 8)
            tile[ty + i][tx] =
                __bfloat162float(in[(size_t)(br + ty + i) * 2048 + bc + tx]) * 4.0f;
        __syncthreads();
        const unsigned int vp = pk4_e4m3(tile[tx][ty], tile[tx][ty + 8],
                                         tile[tx][ty + 16], tile[tx][ty + 24]);
#pragma unroll
        for (int i = 0; i < 4; ++i)
            out[(size_t)(bc + ty + i * 8) * 1024 + br + tx] =
                (unsigned char)(vp >> (8 * i));
        return;
    }

    const int side = flat >> 11;
    const int idx  = flat & 2047;
    const int h    = idx & 7;              // head-adjacent ordering
    const int r0   = (idx >> 3) * 16;

    const ScArgs g = P.s[side];
    const int t    = threadIdx.x;
    const int lane = t & 63;
    const int w    = t >> 6;
    const int fr   = lane & 15;
    const int fq   = lane >> 4;
    const int cbase = w * 256;

    const short* Qs = (const short*)g.Q + (size_t)(r0 + fr) * 512 + h * 64 + fq * 8;
    short8 a0 = *(const short8*)(Qs);
    short8 a1 = *(const short8*)(Qs + 32);

    floatx4 accs[16];
    const short* Kb = (const short*)g.K + h * 64 + fq * 8;
#pragma unroll
    for (int c = 0; c < 16; ++c) {
        const int krow = cbase + c * 16 + fr;
        short8 b0 = *(const short8*)(Kb + (size_t)krow * ldk);
        short8 b1 = *(const short8*)(Kb + (size_t)krow * ldk + 32);
        floatx4 acc = {0.f, 0.f, 0.f, 0.f};
        acc = __builtin_amdgcn_mfma_f32_16x16x32_bf16(a0, b0, acc, 0, 0, 0);
        acc = __builtin_amdgcn_mfma_f32_16x16x32_bf16(a1, b1, acc, 0, 0, 0);
        accs[c] = acc;
    }

    float mxr[4] = {-3e38f, -3e38f, -3e38f, -3e38f};
#pragma unroll
    for (int c = 0; c < 16; ++c) {
        const int col = cbase + c * 16 + fr;
#pragma unroll
        for (int r = 0; r < 4; ++r) {
            const int row = r0 + fq * 4 + r;
            float v = (g.mask[(size_t)row * 1024 + col] == 0) ? -1e9f
                                                              : accs[c][r] * scale;
            accs[c][r] = v;
            mxr[r] = fmaxf(mxr[r], v);
        }
    }
#pragma unroll
    for (int o = 1; o < 16; o <<= 1)
#pragma unroll
        for (int r = 0; r < 4; ++r) mxr[r] = fmaxf(mxr[r], __shfl_xor(mxr[r], o));
    if (fr == 0)
#pragma unroll
        for (int r = 0; r < 4; ++r) wred[fq * 4 + r][w] = mxr[r];
    __syncthreads();

    float mx[4], sm[4] = {0.f, 0.f, 0.f, 0.f};
#pragma unroll
    for (int r = 0; r < 4; ++r) {
        const int row = fq * 4 + r;
        mx[r] = fmaxf(fmaxf(wred[row][0], wred[row][1]),
                      fmaxf(wred[row][2], wred[row][3]));
    }
#pragma unroll
    for (int c = 0; c < 16; ++c)
#pragma unroll
        for (int r = 0; r < 4; ++r) {
            float e = __expf(accs[c][r] - mx[r]);
            accs[c][r] = e;
            sm[r] += e;
        }
#pragma unroll
    for (int o = 1; o < 16; o <<= 1)
#pragma unroll
        for (int r = 0; r < 4; ++r) sm[r] += __shfl_xor(sm[r], o);
    if (fr == 0)
#pragma unroll
        for (int r = 0; r < 4; ++r) wsum[fq * 4 + r][w] = sm[r];
    __syncthreads();

    float inv[4];
#pragma unroll
    for (int r = 0; r < 4; ++r) {
        const int row = fq * 4 + r;
        inv[r] = 32.0f / (wsum[row][0] + wsum[row][1] + wsum[row][2] + wsum[row][3]);
    }
    unsigned char* awtb = g.awt + (size_t)(r0 >> 4) * 131072 + fq * 4;
#pragma unroll
    for (int c = 0; c < 16; ++c) {
        const int col = cbase + c * 16 + fr;
        const unsigned int pk = pk4_e4m3(accs[c][0] * inv[0], accs[c][1] * inv[1],
                                         accs[c][2] * inv[2], accs[c][3] * inv[3]);
#pragma unroll
        for (int r = 0; r < 4; ++r)
            g.aw[(size_t)(r0 + fq * 4 + r) * 8192 + h * 1024 + col] =
                (unsigned char)(pk >> (8 * r));
        // chunk-plane transposed store: contiguous 256B per wave store
        *(unsigned int*)(awtb + (size_t)(h * 1024 + col) * 16) = pk;
    }
}

// ---------------------------------------------------------------------------
// fp8 ctx GEMM (BK=64, XOR swizzle) with fused bf16 C + quantized-transposed
// CT = e4m3(C*16) output. BM=BN=64. Double-buffered, counted vmcnt(2)
// (T3/T4): tile t+1's loads stay in flight across the barrier.
// ---------------------------------------------------------------------------
struct B8Args { const unsigned char* A; const unsigned char* B; bf16* C;
                unsigned char* CT; };
struct B8Pair { B8Args s[2]; };

__global__ __launch_bounds__(256) void gemm_bt8_ctx(
    B8Pair P, int lda, long long a_kshift, int ldb, int ldc, int ldct,
    int K, float scale)
{
    constexpr int TM = 2, TN = 2;
    __align__(16) __shared__ unsigned char As[2][64 * 64];
    __align__(16) __shared__ unsigned char Bs[2][64 * 64];

    const B8Args g = P.s[blockIdx.z];
    const int lane = threadIdx.x & 63;
    const int wv   = threadIdx.x >> 6;
    const int m_base = blockIdx.y * 64;
    const int n_base = blockIdx.x * 64;
    const unsigned char* A = g.A + (long long)blockIdx.x * a_kshift;

    const int wm0 = (wv >> 1) * 32;
    const int wn0 = (wv & 1) * 32;

    floatx4 zero = {0.f, 0.f, 0.f, 0.f};
    floatx4 acc[TM][TN];
#pragma unroll
    for (int mt = 0; mt < TM; ++mt)
#pragma unroll
        for (int nt = 0; nt < TN; ++nt) acc[mt][nt] = zero;

    const int ar = lane >> 2;
    const int ac = (((lane & 3) ^ (ar & 3)) * 16);
    const int fr = lane & 15;
    const int q  = lane >> 4;
    const int sw = fr & 3;

    const int NT = K >> 6;              // 16 K-tiles (K=1024)

    auto stage = [&](int tt, int b) {
        const int k0 = tt << 6;
        async16(A + (size_t)(m_base + wv * 16 + ar) * lda + k0 + ac,
                &As[b][wv * 16 * 64]);
        async16(g.B + (size_t)(n_base + wv * 16 + ar) * ldb + k0 + ac,
                &Bs[b][wv * 16 * 64]);
    };

    stage(0, 0);
    stage(1, 1);                        // 4 loads in flight per wave

    for (int t = 0; t < NT; ++t) {
        const int cur = t & 1;
        if (t + 1 < NT)
            asm volatile("s_waitcnt vmcnt(2)\n\ts_barrier" ::: "memory");
        else
            asm volatile("s_waitcnt vmcnt(0)\n\ts_barrier" ::: "memory");

#pragma unroll
        for (int s = 0; s < 2; ++s) {
            const int boff = (((s * 2 + (q >> 1)) ^ sw) * 16) + (q & 1) * 8;
            long af[TM], bfr[TN];
#pragma unroll
            for (int mt = 0; mt < TM; ++mt)
                af[mt] = *(const long*)&As[cur][(wm0 + mt * 16 + fr) * 64 + boff];
#pragma unroll
            for (int nt = 0; nt < TN; ++nt)
                bfr[nt] = *(const long*)&Bs[cur][(wn0 + nt * 16 + fr) * 64 + boff];
#pragma unroll
            for (int mt = 0; mt < TM; ++mt)
#pragma unroll
                for (int nt = 0; nt < TN; ++nt)
                    acc[mt][nt] = __builtin_amdgcn_mfma_f32_16x16x32_fp8_fp8(
                        af[mt], bfr[nt], acc[mt][nt], 0, 0, 0);
        }
        // all waves done READING buf[cur] before anyone restages into it
        asm volatile("s_barrier" ::: "memory");
        if (t + 2 < NT) stage(t + 2, cur);
    }

    const int er = lane >> 4;
    const int ec = lane & 15;
#pragma unroll
    for (int nt = 0; nt < TN; ++nt) {
        const int col = n_base + wn0 + nt * 16 + ec;
#pragma unroll
        for (int mt = 0; mt < TM; ++mt) {
            const int rowb = m_base + wm0 + mt * 16 + er * 4;
            float v0 = fmaxf(acc[mt][nt][0] * scale, 0.f);
            float v1 = fmaxf(acc[mt][nt][1] * scale, 0.f);
            float v2 = fmaxf(acc[mt][nt][2] * scale, 0.f);
            float v3 = fmaxf(acc[mt][nt][3] * scale, 0.f);
            g.C[(size_t)(rowb + 0) * ldc + col] = __float2bfloat16(v0);
            g.C[(size_t)(rowb + 1) * ldc + col] = __float2bfloat16(v1);
            g.C[(size_t)(rowb + 2) * ldc + col] = __float2bfloat16(v2);
            g.C[(size_t)(rowb + 3) * ldc + col] = __float2bfloat16(v3);
            const unsigned int pk = pk4_e4m3(v0 * 16.f, v1 * 16.f, v2 * 16.f, v3 * 16.f);
            *(unsigned int*)(g.CT + (size_t)col * ldct + rowb) = pk;
        }
    }
}

// ---------------------------------------------------------------------------
// MX-scaled fp8 C = A*B^T, BK=128, unit e8m0 scales. ADDC0: +bf16 C0.
// FP8OUT: e4m3 row-major out; TOUT: also e4m3 transposed out (4-row u32).
// ldbk: B K-chunk stride — standard row-major B passes ldbk=16; the
// chunk-plane awt layout passes ldb=16, ldbk=131072.
// DBUF: double-buffered LDS + counted vmcnt(8) (T3/T4) — loads of tile t+1
// stay in flight across the barrier; only used for the fn instantiation
// (BM=BN=128 -> 8 loads/wave/stage, LDS 64KB, still 2 blocks/CU). The
// BM=512 t1 instantiation stays single-buffered (dbuf would force
// 1 block/CU -> the r1/r5 occupancy trap).
// Inner loop preloads B-fragments and iterates mt; per-acc accumulation
// order identical in all variants -> bit-identical results.
// ---------------------------------------------------------------------------
struct MxArgs { const unsigned char* A; const unsigned char* B; void* C;
                const bf16* Cz; unsigned char* CT; };
struct MxPair { MxArgs s[2]; };

template <int BM, int BN, bool ADDC0, bool FP8OUT, bool TOUT, bool DBUF>
__global__ __launch_bounds__(256, 2) void gemm_bt8mx(
    MxPair P, int lda, int ldb, int ldbk, int ldc, int ldc0, int ldct,
    int K, float scale)
{
    constexpr int WM = BM / 2;
    constexpr int WN = BN / 2;
    constexpr int TM = WM / 16;
    constexpr int TN = WN / 16;
    static_assert(!DBUF || (BM / 32 + BN / 32) == 8, "DBUF assumes vmcnt(8)");

    __align__(16) __shared__ unsigned char As[(DBUF ? 2 : 1) * BM * 128];
    __align__(16) __shared__ unsigned char Bs[(DBUF ? 2 : 1) * BN * 128];

    const MxArgs g = P.s[blockIdx.z];
    const int lane = threadIdx.x & 63;
    const int wv   = threadIdx.x >> 6;
    const int m_base = blockIdx.y * BM;
    const int n_base = blockIdx.x * BN;

    const int wm0 = (wv >> 1) * WM;
    const int wn0 = (wv & 1) * WN;

    floatx4 zero = {0.f, 0.f, 0.f, 0.f};
    floatx4 acc[TM][TN];
#pragma unroll
    for (int mt = 0; mt < TM; ++mt)
#pragma unroll
        for (int nt = 0; nt < TN; ++nt) acc[mt][nt] = zero;

    const int sr = lane >> 3;
    const int sc = ((lane & 7) ^ sr) * 16;
    const int fr = lane & 15;
    const int q  = lane >> 4;
    const int sw = fr & 7;

    auto stage = [&](int k0, int b) {
        unsigned char* Ab = As + b * (BM * 128);
        unsigned char* Bb = Bs + b * (BN * 128);
#pragma unroll
        for (int cc = 0; cc < BM / 32; ++cc) {
            const int r0t = (wv + cc * 4) * 8;
            async16(g.A + (size_t)(m_base + r0t + sr) * lda + k0 + sc, Ab + r0t * 128);
        }
#pragma unroll
        for (int cc = 0; cc < BN / 32; ++cc) {
            const int r0t = (wv + cc * 4) * 8;
            async16(g.B + (size_t)(n_base + r0t + sr) * ldb +
                        (size_t)((k0 + sc) >> 4) * ldbk, Bb + r0t * 128);
        }
    };

    auto compute = [&](int b) {
        const unsigned char* Ab = As + b * (BM * 128);
        const unsigned char* Bb = Bs + b * (BN * 128);
        i32x8 bfr[TN];
#pragma unroll
        for (int nt = 0; nt < TN; ++nt) {
            const unsigned char* rp = &Bb[(wn0 + nt * 16 + fr) * 128];
            i32x4 lo = *(const i32x4*)(rp + (((q * 2 + 0) ^ sw) * 16));
            i32x4 hi = *(const i32x4*)(rp + (((q * 2 + 1) ^ sw) * 16));
            bfr[nt] = __builtin_shufflevector(lo, hi, 0, 1, 2, 3, 4, 5, 6, 7);
        }
#pragma unroll
        for (int mt = 0; mt < TM; ++mt) {
            const unsigned char* rp = &Ab[(wm0 + mt * 16 + fr) * 128];
            i32x4 lo = *(const i32x4*)(rp + (((q * 2 + 0) ^ sw) * 16));
            i32x4 hi = *(const i32x4*)(rp + (((q * 2 + 1) ^ sw) * 16));
            i32x8 af = __builtin_shufflevector(lo, hi, 0, 1, 2, 3, 4, 5, 6, 7);
#pragma unroll
            for (int nt = 0; nt < TN; ++nt)
                acc[mt][nt] = __builtin_amdgcn_mfma_scale_f32_16x16x128_f8f6f4(
                    af, bfr[nt], acc[mt][nt], 0, 0, 0, 127, 0, 127);
        }
    };

    if constexpr (DBUF) {
        const int NT = K >> 7;
        stage(0, 0);
        stage(128, 1);
        for (int t = 0; t < NT; ++t) {
            const int cur = t & 1;
            if (t + 1 < NT)
                asm volatile("s_waitcnt vmcnt(8)\n\ts_barrier" ::: "memory");
            else
                asm volatile("s_waitcnt vmcnt(0)\n\ts_barrier" ::: "memory");
            compute(cur);
            asm volatile("s_barrier" ::: "memory");
            if (t + 2 < NT) stage((t + 2) << 7, cur);
        }
    } else {
        for (int k0 = 0; k0 < K; k0 += 128) {
            stage(k0, 0);
            __syncthreads();
            compute(0);
            __syncthreads();
        }
    }

    const int er = lane >> 4;
    const int ec = lane & 15;
#pragma unroll
    for (int nt = 0; nt < TN; ++nt) {
        const int col = n_base + wn0 + nt * 16 + ec;
#pragma unroll
        for (int mt = 0; mt < TM; ++mt) {
            const int rowb = m_base + wm0 + mt * 16 + er * 4;
            float v[4];
#pragma unroll
            for (int r = 0; r < 4; ++r) {
                v[r] = acc[mt][nt][r] * scale;
                if constexpr (ADDC0)
                    v[r] += __bfloat162float(g.Cz[(size_t)(rowb + r) * ldc0 + col]);
            }
            if constexpr (FP8OUT) {
                const unsigned int pk = pk4_e4m3(v[0], v[1], v[2], v[3]);
#pragma unroll
                for (int r = 0; r < 4; ++r)
                    ((unsigned char*)g.C)[(size_t)(rowb + r) * ldc + col] =
                        (unsigned char)(pk >> (8 * r));
                if constexpr (TOUT)
                    *(unsigned int*)(g.CT + (size_t)col * ldct + rowb) = pk;
            } else {
#pragma unroll
                for (int r = 0; r < 4; ++r)
                    ((bf16*)g.C)[(size_t)(rowb + r) * ldc + col] = __float2bfloat16(v[r]);
            }
        }
    }
}

// ---------------------------------------------------------------------------
// Merged LayerNorm over 8192 rows x 256 cols; flag sniffed inline.
// ---------------------------------------------------------------------------
__global__ __launch_bounds__(256) void ln_all(
    const float* __restrict__ X,
    const bf16* __restrict__ g1, const bf16* __restrict__ be1,
    const bf16* __restrict__ g2, const bf16* __restrict__ be2,
    void* __restrict__ out, const unsigned short* __restrict__ sn)
{
    const bool f32 = sniff_wave(sn);
    const int lane = threadIdx.x & 63;
    const int wv   = threadIdx.x >> 6;
    const int row  = blockIdx.x * 4 + wv;
    const bf16* gg = (row >= 4096) ? g2 : g1;
    const bf16* bb = (row >= 4096) ? be2 : be1;
    const float* x = X + (size_t)row * 256;
    float v[4], s = 0.f, s2 = 0.f;
#pragma unroll
    for (int i = 0; i < 4; ++i) {
        v[i] = x[lane + 64 * i];
        s += v[i]; s2 += v[i] * v[i];
    }
#pragma unroll
    for (int o = 1; o < 64; o <<= 1) { s += __shfl_xor(s, o); s2 += __shfl_xor(s2, o); }
    const float mu  = s * (1.0f / 256.0f);
    const float var = fmaxf(s2 * (1.0f / 256.0f) - mu * mu, 0.0f);
    const float inv = rsqrtf(var + 1e-5f);
#pragma unroll
    for (int i = 0; i < 4; ++i) {
        const int c = lane + 64 * i;
        const float y = (v[i] - mu) * inv * __bfloat162float(gg[c]) + __bfloat162float(bb[c]);
        if (f32) ((float*)out)[(size_t)row * 256 + c] = y;
        else     ((bf16*)out)[(size_t)row * 256 + c] = __float2bfloat16(y);
    }
}

// ---------------------------------------------------------------------------
extern "C" void kernel_launch(void* const* d_in, const int* in_sizes, int n_in,
                              void* d_out, int out_size, void* d_ws, size_t ws_size,
                              hipStream_t stream)
{
    const int L = 4096, Mm = 1024, P = 4096;

    const int* mask_l = (const int*)d_in[3];
    const int* mask_p = (const int*)d_in[4];
    const unsigned short* sn = (const unsigned short*)d_in[0];

    char* ws = (char*)d_ws;
    size_t off = 0;
    auto alloc = [&](size_t bytes) {
        void* p = ws + off; off += (bytes + 255) & ~(size_t)255; return p;
    };

    // weight slots: 0:Wl 1:Wm 2:Wp 3:Wql 4:Wqp 5:Wkl 6:Wvl 7:Wkp 8:Wvp
    bf16* wt_all = (bf16*)alloc((size_t)9 * 512 * 512 * 2);
    bf16* WmlT   = (bf16*)alloc(1024 * 256 * 2);
    bf16* WmpT   = (bf16*)alloc(1024 * 256 * 2);
    bf16* b_l    = (bf16*)alloc(512 * 2);
    bf16* b_m    = (bf16*)alloc(512 * 2);
    bf16* b_p    = (bf16*)alloc(512 * 2);
    bf16* b_ql   = (bf16*)alloc(512 * 2);
    bf16* b_qp   = (bf16*)alloc(512 * 2);
    bf16* bcat   = (bf16*)alloc(2048 * 2);     // [bkl|bvl|bkp|bvp]
    bf16* bml_c  = (bf16*)alloc(256 * 2);
    bf16* bmp_c  = (bf16*)alloc(256 * 2);
    bf16* g1c    = (bf16*)alloc(256 * 2);
    bf16* be1c   = (bf16*)alloc(256 * 2);
    bf16* g2c    = (bf16*)alloc(256 * 2);
    bf16* be2c   = (bf16*)alloc(256 * 2);
    bf16* emb_all = (bf16*)alloc((size_t)(L + Mm + P) * 512 * 2);  // [l|m|p]
    bf16* embl   = emb_all;
    bf16* embm   = emb_all + (size_t)L * 512;
    bf16* embp   = embm + (size_t)Mm * 512;
    bf16* cat_l  = (bf16*)alloc((size_t)L * 1024 * 2);   // [lt | fin_l]
    bf16* cat_p  = (bf16*)alloc((size_t)P * 1024 * 2);   // [fin_p | pt]
    bf16* mt     = (bf16*)alloc((size_t)Mm * 512 * 2);
    bf16* Ql     = (bf16*)alloc((size_t)L * 512 * 2);
    bf16* Qp     = (bf16*)alloc((size_t)P * 512 * 2);
    bf16* kvcat  = (bf16*)alloc((size_t)Mm * 2048 * 2);  // [Kl|Vl|Kp|Vp]
    unsigned char* V8lT = (unsigned char*)alloc((size_t)512 * Mm);
    unsigned char* V8pT = (unsigned char*)alloc((size_t)512 * Mm);
    bf16* ctx_l  = (bf16*)alloc((size_t)L * 512 * 2);
    bf16* ctx_p  = (bf16*)alloc((size_t)P * 512 * 2);
    unsigned char* ctx8lT = (unsigned char*)alloc((size_t)512 * L);
    unsigned char* ctx8pT = (unsigned char*)alloc((size_t)512 * P);
    unsigned char* awlT8  = (unsigned char*)alloc((size_t)8192 * 4096);  // aw_l^T planes
    unsigned char* awpT8  = (unsigned char*)alloc((size_t)8192 * 4096);  // aw_p^T planes
    unsigned char* awl8 = (unsigned char*)alloc((size_t)L * 8192);
    unsigned char* awp8 = (unsigned char*)alloc((size_t)P * 8192);
    unsigned char* m8l  = (unsigned char*)alloc((size_t)L * 1024);       // mask u8
    unsigned char* m8p  = (unsigned char*)alloc((size_t)P * 1024);
    // overlays: emb_all dead after step 2 -> hosts T1 (8MB <= 9.4MB);
    // awp8 dead after step 7 -> tmp written in step 8
    unsigned char* T1lT = (unsigned char*)emb_all;                       // [512,8192]
    unsigned char* T1pT = (unsigned char*)emb_all + (size_t)512 * 8192;  // [512,8192]
    float* tmp1 = (float*)awp8;                          // [8192, 256] fp32

    // 1. unified prep: 18 converts + 9 square + 2 rect transposes + 2 masks
    PrepArgs pa;
    pa.sn = sn;
    pa.cv[0]  = { d_in[0],  embl, L * 512 };
    pa.cv[1]  = { d_in[1],  embm, Mm * 512 };
    pa.cv[2]  = { d_in[2],  embp, P * 512 };
    pa.cv[3]  = { d_in[6],  b_l,  512 };
    pa.cv[4]  = { d_in[8],  b_m,  512 };
    pa.cv[5]  = { d_in[10], b_p,  512 };
    pa.cv[6]  = { d_in[12], b_ql, 512 };
    pa.cv[7]  = { d_in[18], b_qp, 512 };
    pa.cv[8]  = { d_in[14], bcat,        512 };
    pa.cv[9]  = { d_in[16], bcat + 512,  512 };
    pa.cv[10] = { d_in[20], bcat + 1024, 512 };
    pa.cv[11] = { d_in[22], bcat + 1536, 512 };
    pa.cv[12] = { d_in[24], bml_c, 256 };
    pa.cv[13] = { d_in[26], bmp_c, 256 };
    pa.cv[14] = { d_in[27], g1c,  256 };
    pa.cv[15] = { d_in[28], be1c, 256 };
    pa.cv[16] = { d_in[29], g2c,  256 };
    pa.cv[17] = { d_in[30], be2c, 256 };
    const int slot_of[9] = {0, 1, 2, 3, 5, 6, 4, 7, 8};
    for (int i = 0; i < 9; ++i) {
        pa.tsrc[i] = d_in[5 + 2 * i];
        pa.tdst[i] = wt_all + (size_t)slot_of[i] * 512 * 512;
    }
    pa.tsrc[9]  = d_in[23]; pa.tdst[9]  = WmlT;
    pa.tsrc[10] = d_in[25]; pa.tdst[10] = WmpT;
    pa.msrc[0] = mask_l; pa.mdst[0] = m8l;
    pa.msrc[1] = mask_p; pa.mdst[1] = m8p;
    prep<<<dim3(256, 31), 256, 0, stream>>>(pa);

    bf16* WlT  = wt_all;
    bf16* WmT  = wt_all + (size_t)1 * 512 * 512;
    bf16* WpT  = wt_all + (size_t)2 * 512 * 512;
    bf16* WqlT = wt_all + (size_t)3 * 512 * 512;
    bf16* WqpT = wt_all + (size_t)4 * 512 * 512;
    bf16* WkvT = wt_all + (size_t)5 * 512 * 512;  // [2048, 512]

    // 2. embedding projections (segment table)
    SegTab st;
    st.W[0] = WlT;  st.bias[0] = b_l; st.C[0] = cat_l;       st.ldc[0] = 1024; st.rs[0] = 0;
    st.W[1] = WmT;  st.bias[1] = b_m; st.C[1] = mt;          st.ldc[1] = 512;  st.rs[1] = 4096;
    st.W[2] = WpT;  st.bias[2] = b_p; st.C[2] = cat_p + 512; st.ldc[2] = 1024; st.rs[2] = 5120;
    gemm_bt_seg<<<dim3(8, 144), 256, 0, stream>>>(emb_all, st, 512);

    // 3. Q projections + KV projection, one launch (z=2 remapped to 32x16)
    BtSet qs;
    qs.s[0] = { cat_l,       WqlT, Ql,    b_ql, 1024, 512, 512 };
    qs.s[1] = { cat_p + 512, WqpT, Qp,    b_qp, 1024, 512, 512 };
    qs.s[2] = { mt,          WkvT, kvcat, bcat, 512,  512, 2048 };
    gemm_btx<false, true><<<dim3(8, 64, 3), 256, 0, stream>>>(qs, 512, 1.0f);

    // 4. scores+softmax + awT (chunk-plane) + V transpose; u8 mask,
    //    head-adjacent ordering
    ScSet sc;
    sc.s[0] = { Ql, kvcat,        m8l, awl8, awlT8 };
    sc.s[1] = { Qp, kvcat + 1024, m8p, awp8, awpT8 };
    sc.vsrc[0] = kvcat + 512;  sc.vdst[0] = V8lT;
    sc.vsrc[1] = kvcat + 1536; sc.vdst[1] = V8pT;
    scores_v8<<<dim3(5120), 256, 0, stream>>>(sc, 2048, 0.125f);

    // 5. ctx = relu(aw @ V) per head, fused ctx8T = e4m3(ctx^T*16);
    //    double-buffered counted-vmcnt K-loop
    B8Pair cx = { { { awl8, V8lT, ctx_l, ctx8lT },
                    { awp8, V8pT, ctx_p, ctx8pT } } };
    gemm_bt8_ctx<<<dim3(8, 64, 2), 256, 0, stream>>>(
        cx, 8192, 1024, 1024, 512, 4096, 1024, 1.0f / 128.0f);

    // 6. RE-ASSOCIATED mutual path: T1lT = ctx8pT @ awpT8^T, K=p=4096.
    //    Tall tile BM=512: awt B-panel read exactly once. Single-buffer
    //    (dbuf would force 1 block/CU).
    MxPair t1 = { { { ctx8pT, awpT8, T1lT, nullptr, nullptr },
                    { ctx8lT, awlT8, T1pT, nullptr, nullptr } } };
    gemm_bt8mx<512, 64, false, true, false, false><<<dim3(128, 1, 2), 256, 0, stream>>>(
        t1, 4096, 16, 131072, 8192, 0, 0, 4096, 1.0f / 128.0f);

    // 7. fn = ctx + (aw @ T1)/8, K=8192; DBUF counted-vmcnt pipeline
    MxPair fn = { { { awl8, T1lT, cat_l + 512, ctx_l, nullptr },
                    { awp8, T1pT, cat_p,       ctx_p, nullptr } } };
    gemm_bt8mx<128, 128, true, false, false, true><<<dim3(4, 32, 2), 256, 0, stream>>>(
        fn, 8192, 8192, 16, 1024, 512, 0, 8192, 1.0f / 1024.0f);

    // 8. final projections (pair, fp32 out)
    BtSet fp;
    fp.s[0] = { cat_l, WmlT, tmp1,                   bml_c, 1024, 1024, 256 };
    fp.s[1] = { cat_p, WmpT, tmp1 + (size_t)L * 256, bmp_c, 1024, 1024, 256 };
    fp.s[2] = fp.s[0];
    gemm_btx<true, false><<<dim3(4, 64, 2), 256, 0, stream>>>(fp, 1024, 1.0f);

    // 9. merged LayerNorm -> d_out
    ln_all<<<dim3(2048), 256, 0, stream>>>(tmp1, g1c, be1c, g2c, be2c, d_out, sn);
}